// Round 1
// baseline (186.033 us; speedup 1.0000x reference)
//
#include <hip/hip_runtime.h>

#define B_  4096
#define G_  31
#define GG_ 961      // G*G
#define P_  8
#define C_  36       // P*(P+1)/2
#define R_  16       // b-values per block

__global__ void zero_kernel(float* out, int n) {
    int i = blockIdx.x * blockDim.x + threadIdx.x;
    if (i < n) out[i] = 0.0f;
}

// Each wave owns 64 consecutive gh cells (one per lane) and R_ consecutive b's.
// Lane loads its cell's 8 params (2x dwordx4, coalesced across the wave),
// computes the 36-pair quadratic form against its register-resident coeffs,
// butterfly-reduces over the 64 gh lanes, lane 0 atomically adds into out[b].
__global__ __launch_bounds__(256, 4)
void quadform_kernel(const float* __restrict__ param,
                     const float* __restrict__ coef,
                     float* __restrict__ out) {
    const int lane    = threadIdx.x & 63;
    const int wv      = threadIdx.x >> 6;            // 4 waves/block
    const int gh_tile = blockIdx.x * 4 + wv;         // 0..15
    const int gh      = gh_tile * 64 + lane;         // 0..1023
    const bool valid  = gh < GG_;
    const int  ghc    = valid ? gh : (GG_ - 1);      // clamp for safe addressing

    // ---- per-lane coeffs (36 floats = 9 float4, 144B stride => 16B aligned) ----
    float cf[C_];
    const float4* cp = reinterpret_cast<const float4*>(coef) + (size_t)ghc * (C_ / 4);
    #pragma unroll
    for (int q = 0; q < C_ / 4; ++q) {
        float4 v = cp[q];
        cf[4*q+0] = v.x; cf[4*q+1] = v.y; cf[4*q+2] = v.z; cf[4*q+3] = v.w;
    }
    if (!valid) {
        #pragma unroll
        for (int c = 0; c < C_; ++c) cf[c] = 0.0f;   // tail lanes contribute 0
    }

    // ---- stream R_ b-values, prefetching the next cell's 32B ----
    const int b0 = blockIdx.y * R_;
    const float4* pb = reinterpret_cast<const float4*>(param);
    size_t idx = ((size_t)b0 * GG_ + ghc) * 2;       // float4 units
    float4 p0 = pb[idx];
    float4 p1 = pb[idx + 1];

    for (int r = 0; r < R_; ++r) {
        const float pv[P_] = {p0.x, p0.y, p0.z, p0.w, p1.x, p1.y, p1.z, p1.w};
        if (r + 1 < R_) {                            // uniform branch: prefetch next b
            size_t nx = idx + (size_t)(r + 1) * (GG_ * 2);
            p0 = pb[nx];
            p1 = pb[nx + 1];
        }
        float s = 0.0f;
        int c = 0;
        #pragma unroll
        for (int i = 0; i < P_; ++i) {
            #pragma unroll
            for (int j = i; j < P_; ++j) {           // np.triu_indices order
                s = fmaf(cf[c] * pv[i], pv[j], s);
                ++c;
            }
        }
        // ---- reduce over the 64 gh-lanes ----
        #pragma unroll
        for (int off = 32; off; off >>= 1) s += __shfl_xor(s, off, 64);
        if (lane == 0) atomicAdd(&out[b0 + r], s);
    }
}

extern "C" void kernel_launch(void* const* d_in, const int* in_sizes, int n_in,
                              void* d_out, int out_size, void* d_ws, size_t ws_size,
                              hipStream_t stream) {
    const float* param = (const float*)d_in[0];   // [B, G, G, P] fp32
    const float* coef  = (const float*)d_in[1];   // [G, G, C]  fp32
    float* out = (float*)d_out;                   // [B] fp32

    zero_kernel<<<(B_ + 255) / 256, 256, 0, stream>>>(out, B_);

    dim3 grid(4, B_ / R_);                        // 4 gh-groups x 256 b-tiles = 1024 blocks
    quadform_kernel<<<grid, 256, 0, stream>>>(param, coef, out);
}

// Round 2
// 183.973 us; speedup vs baseline: 1.0112x; 1.0112x over previous
//
#include <hip/hip_runtime.h>

#define B_  4096
#define G_  31
#define GG_ 961      // G*G
#define P_  8
#define C_  36       // P*(P+1)/2
#define R_  8        // b-values per block

__global__ void zero_kernel(float* out, int n) {
    int i = blockIdx.x * blockDim.x + threadIdx.x;
    if (i < n) out[i] = 0.0f;
}

// Lane owns one gh cell (coeffs register-resident), block covers 256 gh x 8 b.
// All 16 dwordx4 param loads issued up front (two 4-b chunks) -> ~16KB MLP/wave.
// 8 independent accumulator chains; interleaved butterflies at the end.
__global__ __launch_bounds__(256, 4)
void quadform_kernel(const float* __restrict__ param,
                     const float* __restrict__ coef,
                     float* __restrict__ out) {
    const int lane    = threadIdx.x & 63;
    const int wv      = threadIdx.x >> 6;            // 4 waves/block
    const int gh_tile = blockIdx.x * 4 + wv;         // 0..15
    const int gh      = gh_tile * 64 + lane;         // 0..1023
    const bool valid  = gh < GG_;
    const int  ghc    = valid ? gh : (GG_ - 1);      // clamp for safe addressing

    // ---- per-lane coeffs (36 floats = 9 float4, 144B stride => 16B aligned) ----
    float cf[C_];
    {
        const float4* cp = reinterpret_cast<const float4*>(coef) + (size_t)ghc * (C_ / 4);
        #pragma unroll
        for (int q = 0; q < C_ / 4; ++q) {
            float4 v = cp[q];
            cf[4*q+0] = v.x; cf[4*q+1] = v.y; cf[4*q+2] = v.z; cf[4*q+3] = v.w;
        }
    }
    if (!valid) {
        #pragma unroll
        for (int c = 0; c < C_; ++c) cf[c] = 0.0f;   // tail lanes contribute 0
    }

    // ---- issue ALL param loads up front: 8 b's x 32B/lane, coalesced ----
    const int b0 = blockIdx.y * R_;
    const float4* pb = reinterpret_cast<const float4*>(param);
    const size_t base = ((size_t)b0 * GG_ + ghc) * 2;   // float4 units
    const size_t bstep = (size_t)GG_ * 2;

    float4 qa[4][2], qb[4][2];
    #pragma unroll
    for (int r = 0; r < 4; ++r) {
        qa[r][0] = pb[base + (size_t)r * bstep];
        qa[r][1] = pb[base + (size_t)r * bstep + 1];
    }
    #pragma unroll
    for (int r = 0; r < 4; ++r) {
        qb[r][0] = pb[base + (size_t)(r + 4) * bstep];
        qb[r][1] = pb[base + (size_t)(r + 4) * bstep + 1];
    }

    // ---- 8 independent quadratic-form chains ----
    float s[R_];
    #pragma unroll
    for (int h = 0; h < 2; ++h) {
        #pragma unroll
        for (int r = 0; r < 4; ++r) {
            float4 p0 = h ? qb[r][0] : qa[r][0];
            float4 p1 = h ? qb[r][1] : qa[r][1];
            const float pv[P_] = {p0.x, p0.y, p0.z, p0.w, p1.x, p1.y, p1.z, p1.w};
            float acc = 0.0f;
            int c = 0;
            #pragma unroll
            for (int i = 0; i < P_; ++i) {
                #pragma unroll
                for (int j = i; j < P_; ++j) {       // np.triu_indices order
                    acc = fmaf(cf[c] * pv[i], pv[j], acc);
                    ++c;
                }
            }
            s[h * 4 + r] = acc;
        }
    }

    // ---- interleaved butterflies: 8 independent shuffle chains ----
    #pragma unroll
    for (int off = 32; off; off >>= 1) {
        #pragma unroll
        for (int r = 0; r < R_; ++r) s[r] += __shfl_xor(s[r], off, 64);
    }

    if (lane == 0) {
        #pragma unroll
        for (int r = 0; r < R_; ++r) atomicAdd(&out[b0 + r], s[r]);
    }
}

extern "C" void kernel_launch(void* const* d_in, const int* in_sizes, int n_in,
                              void* d_out, int out_size, void* d_ws, size_t ws_size,
                              hipStream_t stream) {
    const float* param = (const float*)d_in[0];   // [B, G, G, P] fp32
    const float* coef  = (const float*)d_in[1];   // [G, G, C]  fp32
    float* out = (float*)d_out;                   // [B] fp32

    zero_kernel<<<(B_ + 255) / 256, 256, 0, stream>>>(out, B_);

    dim3 grid(4, B_ / R_);                        // 4 gh-groups x 512 b-tiles = 2048 blocks
    quadform_kernel<<<grid, 256, 0, stream>>>(param, coef, out);
}